// Round 3
// baseline (18.540 us; speedup 1.0000x reference)
//
#include <hip/hip_runtime.h>
#include <stdint.h>

#define M_MACH 50
#define N_JOBS 100
#define NFEAT 5400        // 50*4 + 100*2 + 50*100
#define A_DIM 32
#define C_DIM 1000
#define INIT_T 16
#define WPB 16            // waves per block (1024 threads)

// One block per action (32 blocks). Each wave scans ~62 clauses: per clause,
// 64 lanes check features 0..63 (all machine-time bits, computed in-register
// once per wave); ta bytes for BOTH planes are loaded and selected by the bit
// so addresses never depend on feature values. A clause surviving chunk 0
// (prob ~4e-19 per clause with this data) takes the full on-the-fly scan.
// Wave partials are LDS-reduced; thread 0 stores out[a] directly -> no
// atomics, no memset, a single graph node.
__global__ __launch_bounds__(1024) void policy_kernel(
    const float* __restrict__ state,
    const int8_t* __restrict__ ta,
    const int8_t* __restrict__ sign,
    float* __restrict__ out) {
    const int lane = threadIdx.x & 63;
    const int wid  = threadIdx.x >> 6;
    const int a    = blockIdx.x;                  // 0..31

    // --- chunk-0 feature bits (features 0..63 = mt bits of machines 0..15) ---
    const float v0 = (lane < M_MACH) ? state[lane] : -1.0f;
    float mx = v0;
    #pragma unroll
    for (int off = 1; off < 64; off <<= 1)
        mx = fmaxf(mx, __shfl_xor(mx, off, 64));
    const float s_i = __shfl(v0, lane >> 2, 64);
    const int norm  = (mx > 0.0f) ? (int)((s_i / mx) * 15.0f) : 0;
    const bool bit  = (norm >> (lane & 3)) & 1;

    // --- scan this action's clauses, hand-prefetched one iteration deep ---
    int psum = 0;
    int c = wid;
    int8_t cin = 0, cex = 0;
    if (c < C_DIM) {
        const int8_t* b = ta + ((size_t)a * C_DIM + c) * (2 * NFEAT);
        cin = b[lane];
        cex = b[NFEAT + lane];
    }
    while (c < C_DIM) {
        const int cn = c + WPB;
        int8_t nin = 0, nex = 0;
        if (cn < C_DIM) {
            const int8_t* b = ta + ((size_t)a * C_DIM + cn) * (2 * NFEAT);
            nin = b[lane];
            nex = b[NFEAT + lane];
        }

        bool violated = __any((bit ? cex : cin) > INIT_T);
        if (!violated) {
            // Rare path: full scan of features 64..5399, bits on the fly.
            const int q = a * C_DIM + c;
            const int8_t* base = ta + (size_t)q * (2 * NFEAT);
            for (int f0 = 64; f0 < NFEAT && !violated; f0 += 64) {
                const int f = f0 + lane;
                bool vv = false;
                if (f < NFEAT) {
                    int b2;
                    if (f < M_MACH * 4) {
                        const int i = f >> 2;
                        const int n2 = (mx > 0.0f) ? (int)((state[i] / mx) * 15.0f) : 0;
                        b2 = (n2 >> (f & 3)) & 1;
                    } else if (f < M_MACH * 4 + N_JOBS * 2) {
                        const int rel = f - M_MACH * 4;
                        int st = (int)(state[M_MACH + (rel >> 1)] * 3.0f);
                        if (st > 3) st = 3;
                        b2 = (st >> (rel & 1)) & 1;
                    } else {
                        b2 = (int)state[M_MACH + N_JOBS + (f - (M_MACH*4 + N_JOBS*2))];
                    }
                    vv = ((b2 ? base[NFEAT + f] : base[f]) > INIT_T);
                }
                violated = __any(vv);
            }
            if (!violated) psum += (int)sign[q];  // uniform across the wave
        }

        cin = nin; cex = nex; c = cn;
    }

    // --- block reduction: 16 wave partials -> out[a] ---
    __shared__ int red[WPB];
    if (lane == 0) red[wid] = psum;
    __syncthreads();
    if (threadIdx.x == 0) {
        int t = 0;
        #pragma unroll
        for (int i = 0; i < WPB; ++i) t += red[i];
        out[a] = (float)t;
    }
}

extern "C" void kernel_launch(void* const* d_in, const int* in_sizes, int n_in,
                              void* d_out, int out_size, void* d_ws, size_t ws_size,
                              hipStream_t stream) {
    const float*  state = (const float*)d_in[0];
    const int8_t* ta    = (const int8_t*)d_in[1];
    const int8_t* sign  = (const int8_t*)d_in[2];
    float* out = (float*)d_out;

    policy_kernel<<<A_DIM, WPB * 64, 0, stream>>>(state, ta, sign, out);
}